// Round 1
// baseline (888.596 us; speedup 1.0000x reference)
//
#include <hip/hip_runtime.h>
#include <hip/hip_bf16.h>

// ---------------------------------------------------------------------------
// HebbianNetwork: logits + 3 coactivation matrices.
//   B=8192, D_IN=1024, H1=H2=2048, N_CLS=1000
// Strategy: bf16 MFMA (16x16x32) 128x128-tile NT gemm for all 6 GEMMs.
// Coacts = ActT @ ActT^T with transposed binarized activations (exact in
// fp32 accumulation since inputs are 0/1).
// ---------------------------------------------------------------------------

#define BM 128
#define BN 128
#define BK 32

typedef short v8s __attribute__((ext_vector_type(8)));
typedef float v4f __attribute__((ext_vector_type(4)));

enum { MODE_RELU = 0, MODE_LOGITS = 1, MODE_F32 = 2 };

__device__ __forceinline__ void async_cp16(const void* gsrc, void* ldst) {
  __builtin_amdgcn_global_load_lds(
      (const __attribute__((address_space(1))) void*)gsrc,
      (__attribute__((address_space(3))) void*)ldst, 16, 0, 0);
}

// C[M,N] = A[M,K] @ B[N,K]^T (+bias), A,B bf16 row-major inner-K.
// MODE_RELU:   store bf16 relu(acc+bias) to Cout [M, ldc]
// MODE_LOGITS: store fp32 (acc+bias) to Cout [M, ldc] for col < n_store
// MODE_F32:    store fp32 acc to Cout [M, ldc] for col < n_store (no bias)
template <int MODE>
__global__ __launch_bounds__(256) void gemm_nt(
    const __hip_bfloat16* __restrict__ A, const __hip_bfloat16* __restrict__ B,
    const float* __restrict__ bias, void* __restrict__ Cout,
    int M, int N, int K, int n_store, int ldc) {
  __shared__ __hip_bfloat16 sA[BM * BK];
  __shared__ __hip_bfloat16 sB[BN * BK];
  const int t = threadIdx.x;
  const int m0 = blockIdx.y * BM;
  const int n0 = blockIdx.x * BN;

  // staging: 128x32 bf16 tile = 8KB; 256 threads x 2 x 16B each
  const int srow = t >> 2;           // 0..63
  const int scol = (t & 3) * 8;      // 0,8,16,24
  const __hip_bfloat16* ag0 = A + (size_t)(m0 + srow) * K + scol;
  const __hip_bfloat16* ag1 = A + (size_t)(m0 + srow + 64) * K + scol;
  const __hip_bfloat16* bg0 = B + (size_t)(n0 + srow) * K + scol;
  const __hip_bfloat16* bg1 = B + (size_t)(n0 + srow + 64) * K + scol;
  char* lA0 = (char*)sA + t * 16;
  char* lA1 = (char*)sA + 4096 + t * 16;
  char* lB0 = (char*)sB + t * 16;
  char* lB1 = (char*)sB + 4096 + t * 16;

  const int lane = t & 63;
  const int wave = t >> 6;
  const int wm = (wave & 1) * 64;
  const int wn = (wave >> 1) * 64;
  const int lrow = lane & 15;
  const int quad = lane >> 4;

  // fragment LDS base pointers (A[m=lane&15][k=quad*8+j] layout)
  const __hip_bfloat16* pa = sA + (wm + lrow) * BK + quad * 8;
  const __hip_bfloat16* pb = sB + (wn + lrow) * BK + quad * 8;

  v4f acc[4][4] = {};

  for (int k0 = 0; k0 < K; k0 += BK) {
    async_cp16(ag0 + k0, lA0);
    async_cp16(ag1 + k0, lA1);
    async_cp16(bg0 + k0, lB0);
    async_cp16(bg1 + k0, lB1);
    __syncthreads();  // compiler drains vmcnt before s_barrier

    v8s af[4], bf[4];
#pragma unroll
    for (int i = 0; i < 4; i++) {
      af[i] = *(const v8s*)(pa + i * 16 * BK);
      bf[i] = *(const v8s*)(pb + i * 16 * BK);
    }
#pragma unroll
    for (int mi = 0; mi < 4; mi++)
#pragma unroll
      for (int ni = 0; ni < 4; ni++)
        acc[mi][ni] = __builtin_amdgcn_mfma_f32_16x16x32_bf16(
            af[mi], bf[ni], acc[mi][ni], 0, 0, 0);
    __syncthreads();
  }

  // epilogue: C/D layout col=lane&15, row=quad*4+reg
#pragma unroll
  for (int ni = 0; ni < 4; ni++) {
    const int col = n0 + wn + ni * 16 + lrow;
    float bv = 0.f;
    if (MODE == MODE_RELU) bv = bias[col];
    if (MODE == MODE_LOGITS && col < n_store) bv = bias[col];
#pragma unroll
    for (int mi = 0; mi < 4; mi++) {
      const int rowb = m0 + wm + mi * 16 + quad * 4;
#pragma unroll
      for (int r = 0; r < 4; r++) {
        const int row = rowb + r;
        const float v = acc[mi][ni][r] + bv;
        if (MODE == MODE_RELU) {
          ((__hip_bfloat16*)Cout)[(size_t)row * ldc + col] =
              __float2bfloat16(v > 0.f ? v : 0.f);
        } else {
          if (col < n_store)
            ((float*)Cout)[(size_t)row * ldc + col] = v;
        }
      }
    }
  }
}

// ---------------------------------------------------------------------------
__device__ __forceinline__ float tofl(float v) { return v; }
__device__ __forceinline__ float tofl(__hip_bfloat16 v) { return __bfloat162float(v); }

// out[c][r] = (in[r][c] > 0) ? 1 : 0 (bf16). out is [Cpad=gridDim.x*64, R].
// Columns >= Cphys produce 0.
template <typename Tin>
__global__ __launch_bounds__(256) void transpose_bin(
    const Tin* __restrict__ in, __hip_bfloat16* __restrict__ out,
    int R, int ldin, int Cphys) {
  __shared__ __hip_bfloat16 tile[64][65];
  const int c0 = blockIdx.x * 64;
  const int r0 = blockIdx.y * 64;
  const int tx = threadIdx.x & 63;
  const int ty = threadIdx.x >> 6;  // 0..3
#pragma unroll
  for (int i = 0; i < 64; i += 4) {
    const int c = c0 + tx;
    const int r = r0 + ty + i;
    float v = 0.f;
    if (c < Cphys) v = tofl(in[(size_t)r * ldin + c]);
    tile[ty + i][tx] = __float2bfloat16(v > 0.f ? 1.f : 0.f);
  }
  __syncthreads();
#pragma unroll
  for (int i = 0; i < 64; i += 4) {
    out[(size_t)(c0 + ty + i) * R + r0 + tx] = tile[tx][ty + i];
  }
}

__global__ __launch_bounds__(256) void f32_to_bf16_k(
    const float* __restrict__ in, __hip_bfloat16* __restrict__ out, int n4) {
  const int i = blockIdx.x * blockDim.x + threadIdx.x;
  if (i < n4) {
    const float4 v = ((const float4*)in)[i];
    union { __hip_bfloat16 h[4]; ushort4 u; } cv;
    cv.h[0] = __float2bfloat16(v.x);
    cv.h[1] = __float2bfloat16(v.y);
    cv.h[2] = __float2bfloat16(v.z);
    cv.h[3] = __float2bfloat16(v.w);
    ((ushort4*)out)[i] = cv.u;
  }
}

// ---------------------------------------------------------------------------
extern "C" void kernel_launch(void* const* d_in, const int* in_sizes, int n_in,
                              void* d_out, int out_size, void* d_ws, size_t ws_size,
                              hipStream_t stream) {
  const float* x  = (const float*)d_in[0];
  const float* W1 = (const float*)d_in[1];
  const float* b1 = (const float*)d_in[2];
  const float* W2 = (const float*)d_in[3];
  const float* b2 = (const float*)d_in[4];
  const float* W3 = (const float*)d_in[5];
  const float* b3 = (const float*)d_in[6];

  float* logits = (float*)d_out;                        // [8192,1000]
  float* coact0 = logits + (size_t)8192 * 1000;         // [1024,2048]
  float* coact1 = coact0 + (size_t)1024 * 2048;         // [2048,2048]
  float* coact2 = coact1 + (size_t)2048 * 2048;         // [2048,1000]

  char* ws = (char*)d_ws;
  size_t off = 0;
  auto alloc = [&](size_t bytes) {
    char* p = ws + off;
    off += (bytes + 255) & ~(size_t)255;
    return p;
  };
  __hip_bfloat16* X   = (__hip_bfloat16*)alloc((size_t)8192 * 1024 * 2);
  __hip_bfloat16* W1b = (__hip_bfloat16*)alloc((size_t)2048 * 1024 * 2);
  __hip_bfloat16* W2b = (__hip_bfloat16*)alloc((size_t)2048 * 2048 * 2);
  __hip_bfloat16* W3b = (__hip_bfloat16*)alloc((size_t)1024 * 2048 * 2);  // padded rows 1000..1023 unused garbage
  __hip_bfloat16* A1  = (__hip_bfloat16*)alloc((size_t)8192 * 2048 * 2);
  __hip_bfloat16* A2  = (__hip_bfloat16*)alloc((size_t)8192 * 2048 * 2);
  __hip_bfloat16* T0  = (__hip_bfloat16*)alloc((size_t)1024 * 8192 * 2);  // Act0^T
  __hip_bfloat16* T1  = (__hip_bfloat16*)alloc((size_t)2048 * 8192 * 2);  // Act1^T
  __hip_bfloat16* T2  = A1;  // Act2^T aliases A1 (dead after gemm2)
  __hip_bfloat16* T3  = A2;  // Act3^T aliases A2 (dead after gemm3)

  const dim3 blk(256);

  // dtype converts
  f32_to_bf16_k<<<8192 * 1024 / 1024, blk, 0, stream>>>(x,  X,   8192 * 1024 / 4);
  f32_to_bf16_k<<<2048 * 1024 / 1024, blk, 0, stream>>>(W1, W1b, 2048 * 1024 / 4);
  f32_to_bf16_k<<<2048 * 2048 / 1024, blk, 0, stream>>>(W2, W2b, 2048 * 2048 / 4);
  f32_to_bf16_k<<<1000 * 2048 / 1024, blk, 0, stream>>>(W3, W3b, 1000 * 2048 / 4);

  // Act0^T = (x>0)^T  [1024, 8192]
  transpose_bin<float><<<dim3(16, 128), blk, 0, stream>>>(x, T0, 8192, 1024, 1024);

  // z1 = X @ W1^T + b1; A1 = relu(z1) bf16
  gemm_nt<MODE_RELU><<<dim3(16, 64), blk, 0, stream>>>(X, W1b, b1, A1,
                                                       8192, 2048, 1024, 2048, 2048);
  // Act1^T [2048, 8192]
  transpose_bin<__hip_bfloat16><<<dim3(32, 128), blk, 0, stream>>>(A1, T1, 8192, 2048, 2048);

  // z2 = A1 @ W2^T + b2; A2 = relu(z2) bf16
  gemm_nt<MODE_RELU><<<dim3(16, 64), blk, 0, stream>>>(A1, W2b, b2, A2,
                                                       8192, 2048, 2048, 2048, 2048);
  // Act2^T [2048, 8192] (aliases A1 — A1 dead now)
  transpose_bin<__hip_bfloat16><<<dim3(32, 128), blk, 0, stream>>>(A2, T2, 8192, 2048, 2048);

  // logits = A2 @ W3^T + b3  (N padded to 1024; store cols < 1000)
  gemm_nt<MODE_LOGITS><<<dim3(8, 64), blk, 0, stream>>>(A2, W3b, b3, logits,
                                                        8192, 1024, 2048, 1000, 1000);
  // Act3^T [1024, 8192] from logits (cols >= 1000 -> 0; aliases A2 — dead now)
  transpose_bin<float><<<dim3(16, 128), blk, 0, stream>>>(logits, T3, 8192, 1000, 1000);

  // coact0 = Act0^T @ Act1  -> [1024, 2048]
  gemm_nt<MODE_F32><<<dim3(16, 8), blk, 0, stream>>>(T0, T1, nullptr, coact0,
                                                     1024, 2048, 8192, 2048, 2048);
  // coact1 = Act1^T @ Act2  -> [2048, 2048]
  gemm_nt<MODE_F32><<<dim3(16, 16), blk, 0, stream>>>(T1, T2, nullptr, coact1,
                                                      2048, 2048, 8192, 2048, 2048);
  // coact2 = Act2^T @ Act3  -> [2048, 1000] (N padded 1024, store < 1000)
  gemm_nt<MODE_F32><<<dim3(8, 16), blk, 0, stream>>>(T2, T3, nullptr, coact2,
                                                     2048, 1024, 8192, 1000, 1000);
}

// Round 2
// 751.963 us; speedup vs baseline: 1.1817x; 1.1817x over previous
//
#include <hip/hip_runtime.h>
#include <hip/hip_bf16.h>

// ---------------------------------------------------------------------------
// HebbianNetwork: logits + 3 coactivation matrices.
//   B=8192, D_IN=1024, H1=H2=2048, N_CLS=1000
// bf16 MFMA (16x16x32) 128x128-tile NT gemm for all 6 GEMMs.
// R1: coact GEMMs were 1 block/CU (175us each, MfmaUtil 15%) -> split-K with
// fp32 atomicAdd epilogue (exact: integer-valued partials < 2^24).
// ---------------------------------------------------------------------------

#define BM 128
#define BN 128
#define BK 32

typedef short v8s __attribute__((ext_vector_type(8)));
typedef float v4f __attribute__((ext_vector_type(4)));

enum { MODE_RELU = 0, MODE_LOGITS = 1, MODE_ATOMIC = 2 };

__device__ __forceinline__ void async_cp16(const void* gsrc, void* ldst) {
  __builtin_amdgcn_global_load_lds(
      (const __attribute__((address_space(1))) void*)gsrc,
      (__attribute__((address_space(3))) void*)ldst, 16, 0, 0);
}

// C[M,N] = A[M,K] @ B[N,K]^T (+bias), A,B bf16 row-major inner-K.
// MODE_RELU:   store bf16 relu(acc+bias) to Cout [M, ldc]
// MODE_LOGITS: store fp32 (acc+bias) to Cout [M, ldc] for col < n_store
// MODE_ATOMIC: atomicAdd fp32 acc into Cout [M, ldc] for col < n_store.
//              K-range handled by this block: [blockIdx.z*Kc, (blockIdx.z+1)*Kc)
template <int MODE>
__global__ __launch_bounds__(256) void gemm_nt(
    const __hip_bfloat16* __restrict__ A, const __hip_bfloat16* __restrict__ B,
    const float* __restrict__ bias, void* __restrict__ Cout,
    int M, int N, int Kc, int n_store, int ldc) {
  __shared__ __hip_bfloat16 sA[BM * BK];
  __shared__ __hip_bfloat16 sB[BN * BK];
  const int t = threadIdx.x;
  const int m0 = blockIdx.y * BM;
  const int n0 = blockIdx.x * BN;
  const int kbeg = blockIdx.z * Kc;
  const int kend = kbeg + Kc;
  const size_t K = (size_t)Kc * gridDim.z;  // full K (row stride)

  // staging: 128x32 bf16 tile = 8KB; 256 threads x 2 x 16B each
  const int srow = t >> 2;           // 0..63
  const int scol = (t & 3) * 8;      // 0,8,16,24
  const __hip_bfloat16* ag0 = A + (size_t)(m0 + srow) * K + scol;
  const __hip_bfloat16* ag1 = A + (size_t)(m0 + srow + 64) * K + scol;
  const __hip_bfloat16* bg0 = B + (size_t)(n0 + srow) * K + scol;
  const __hip_bfloat16* bg1 = B + (size_t)(n0 + srow + 64) * K + scol;
  char* lA0 = (char*)sA + t * 16;
  char* lA1 = (char*)sA + 4096 + t * 16;
  char* lB0 = (char*)sB + t * 16;
  char* lB1 = (char*)sB + 4096 + t * 16;

  const int lane = t & 63;
  const int wave = t >> 6;
  const int wm = (wave & 1) * 64;
  const int wn = (wave >> 1) * 64;
  const int lrow = lane & 15;
  const int quad = lane >> 4;

  // fragment LDS base pointers (A[m=lane&15][k=quad*8+j] layout)
  const __hip_bfloat16* pa = sA + (wm + lrow) * BK + quad * 8;
  const __hip_bfloat16* pb = sB + (wn + lrow) * BK + quad * 8;

  v4f acc[4][4] = {};

  for (int k0 = kbeg; k0 < kend; k0 += BK) {
    async_cp16(ag0 + k0, lA0);
    async_cp16(ag1 + k0, lA1);
    async_cp16(bg0 + k0, lB0);
    async_cp16(bg1 + k0, lB1);
    __syncthreads();  // compiler drains vmcnt before s_barrier

    v8s af[4], bf[4];
#pragma unroll
    for (int i = 0; i < 4; i++) {
      af[i] = *(const v8s*)(pa + i * 16 * BK);
      bf[i] = *(const v8s*)(pb + i * 16 * BK);
    }
#pragma unroll
    for (int mi = 0; mi < 4; mi++)
#pragma unroll
      for (int ni = 0; ni < 4; ni++)
        acc[mi][ni] = __builtin_amdgcn_mfma_f32_16x16x32_bf16(
            af[mi], bf[ni], acc[mi][ni], 0, 0, 0);
    __syncthreads();
  }

  // epilogue: C/D layout col=lane&15, row=quad*4+reg
#pragma unroll
  for (int ni = 0; ni < 4; ni++) {
    const int col = n0 + wn + ni * 16 + lrow;
    float bv = 0.f;
    if (MODE == MODE_RELU) bv = bias[col];
    if (MODE == MODE_LOGITS && col < n_store) bv = bias[col];
#pragma unroll
    for (int mi = 0; mi < 4; mi++) {
      const int rowb = m0 + wm + mi * 16 + quad * 4;
#pragma unroll
      for (int r = 0; r < 4; r++) {
        const int row = rowb + r;
        const float v = acc[mi][ni][r] + bv;
        if (MODE == MODE_RELU) {
          ((__hip_bfloat16*)Cout)[(size_t)row * ldc + col] =
              __float2bfloat16(v > 0.f ? v : 0.f);
        } else if (MODE == MODE_LOGITS) {
          if (col < n_store)
            ((float*)Cout)[(size_t)row * ldc + col] = v;
        } else {
          if (col < n_store)
            atomicAdd(&((float*)Cout)[(size_t)row * ldc + col], v);
        }
      }
    }
  }
}

// ---------------------------------------------------------------------------
__device__ __forceinline__ float tofl(float v) { return v; }
__device__ __forceinline__ float tofl(__hip_bfloat16 v) { return __bfloat162float(v); }

// out[c][r] = (in[r][c] > 0) ? 1 : 0 (bf16). out is [Cpad=gridDim.x*64, R].
// Columns >= Cphys produce 0.
template <typename Tin>
__global__ __launch_bounds__(256) void transpose_bin(
    const Tin* __restrict__ in, __hip_bfloat16* __restrict__ out,
    int R, int ldin, int Cphys) {
  __shared__ __hip_bfloat16 tile[64][65];
  const int c0 = blockIdx.x * 64;
  const int r0 = blockIdx.y * 64;
  const int tx = threadIdx.x & 63;
  const int ty = threadIdx.x >> 6;  // 0..3
#pragma unroll
  for (int i = 0; i < 64; i += 4) {
    const int c = c0 + tx;
    const int r = r0 + ty + i;
    float v = 0.f;
    if (c < Cphys) v = tofl(in[(size_t)r * ldin + c]);
    tile[ty + i][tx] = __float2bfloat16(v > 0.f ? 1.f : 0.f);
  }
  __syncthreads();
#pragma unroll
  for (int i = 0; i < 64; i += 4) {
    out[(size_t)(c0 + ty + i) * R + r0 + tx] = tile[tx][ty + i];
  }
}

__global__ __launch_bounds__(256) void f32_to_bf16_k(
    const float* __restrict__ in, __hip_bfloat16* __restrict__ out, int n4) {
  const int i = blockIdx.x * blockDim.x + threadIdx.x;
  if (i < n4) {
    const float4 v = ((const float4*)in)[i];
    union { __hip_bfloat16 h[4]; ushort4 u; } cv;
    cv.h[0] = __float2bfloat16(v.x);
    cv.h[1] = __float2bfloat16(v.y);
    cv.h[2] = __float2bfloat16(v.z);
    cv.h[3] = __float2bfloat16(v.w);
    ((ushort4*)out)[i] = cv.u;
  }
}

// ---------------------------------------------------------------------------
extern "C" void kernel_launch(void* const* d_in, const int* in_sizes, int n_in,
                              void* d_out, int out_size, void* d_ws, size_t ws_size,
                              hipStream_t stream) {
  const float* x  = (const float*)d_in[0];
  const float* W1 = (const float*)d_in[1];
  const float* b1 = (const float*)d_in[2];
  const float* W2 = (const float*)d_in[3];
  const float* b2 = (const float*)d_in[4];
  const float* W3 = (const float*)d_in[5];
  const float* b3 = (const float*)d_in[6];

  float* logits = (float*)d_out;                        // [8192,1000]
  float* coact0 = logits + (size_t)8192 * 1000;         // [1024,2048]
  float* coact1 = coact0 + (size_t)1024 * 2048;         // [2048,2048]
  float* coact2 = coact1 + (size_t)2048 * 2048;         // [2048,1000]

  char* ws = (char*)d_ws;
  size_t off = 0;
  auto alloc = [&](size_t bytes) {
    char* p = ws + off;
    off += (bytes + 255) & ~(size_t)255;
    return p;
  };
  __hip_bfloat16* X   = (__hip_bfloat16*)alloc((size_t)8192 * 1024 * 2);
  __hip_bfloat16* W1b = (__hip_bfloat16*)alloc((size_t)2048 * 1024 * 2);
  __hip_bfloat16* W2b = (__hip_bfloat16*)alloc((size_t)2048 * 2048 * 2);
  __hip_bfloat16* W3b = (__hip_bfloat16*)alloc((size_t)1024 * 2048 * 2);  // padded rows 1000..1023 unused garbage
  __hip_bfloat16* A1  = (__hip_bfloat16*)alloc((size_t)8192 * 2048 * 2);
  __hip_bfloat16* A2  = (__hip_bfloat16*)alloc((size_t)8192 * 2048 * 2);
  __hip_bfloat16* T0  = (__hip_bfloat16*)alloc((size_t)1024 * 8192 * 2);  // Act0^T
  __hip_bfloat16* T1  = (__hip_bfloat16*)alloc((size_t)2048 * 8192 * 2);  // Act1^T
  __hip_bfloat16* T2  = A1;  // Act2^T aliases A1 (dead after gemm2)
  __hip_bfloat16* T3  = A2;  // Act3^T aliases A2 (dead after gemm3)

  const dim3 blk(256);

  // zero the three coact outputs (split-K accumulates atomically into them)
  hipMemsetAsync(coact0, 0,
                 ((size_t)1024 * 2048 + (size_t)2048 * 2048 + (size_t)2048 * 1000) * 4,
                 stream);

  // dtype converts
  f32_to_bf16_k<<<8192 * 1024 / 1024, blk, 0, stream>>>(x,  X,   8192 * 1024 / 4);
  f32_to_bf16_k<<<2048 * 1024 / 1024, blk, 0, stream>>>(W1, W1b, 2048 * 1024 / 4);
  f32_to_bf16_k<<<2048 * 2048 / 1024, blk, 0, stream>>>(W2, W2b, 2048 * 2048 / 4);
  f32_to_bf16_k<<<1000 * 2048 / 1024, blk, 0, stream>>>(W3, W3b, 1000 * 2048 / 4);

  // Act0^T = (x>0)^T  [1024, 8192]
  transpose_bin<float><<<dim3(16, 128), blk, 0, stream>>>(x, T0, 8192, 1024, 1024);

  // z1 = X @ W1^T + b1; A1 = relu(z1) bf16
  gemm_nt<MODE_RELU><<<dim3(16, 64), blk, 0, stream>>>(X, W1b, b1, A1,
                                                       8192, 2048, 1024, 2048, 2048);
  // Act1^T [2048, 8192]
  transpose_bin<__hip_bfloat16><<<dim3(32, 128), blk, 0, stream>>>(A1, T1, 8192, 2048, 2048);

  // z2 = A1 @ W2^T + b2; A2 = relu(z2) bf16
  gemm_nt<MODE_RELU><<<dim3(16, 64), blk, 0, stream>>>(A1, W2b, b2, A2,
                                                       8192, 2048, 2048, 2048, 2048);
  // Act2^T [2048, 8192] (aliases A1 — A1 dead now)
  transpose_bin<__hip_bfloat16><<<dim3(32, 128), blk, 0, stream>>>(A2, T2, 8192, 2048, 2048);

  // logits = A2 @ W3^T + b3  (N padded to 1024; store cols < 1000)
  gemm_nt<MODE_LOGITS><<<dim3(8, 64), blk, 0, stream>>>(A2, W3b, b3, logits,
                                                        8192, 1024, 2048, 1000, 1000);
  // Act3^T [1024, 8192] from logits (cols >= 1000 -> 0; aliases A2 — dead now)
  transpose_bin<float><<<dim3(16, 128), blk, 0, stream>>>(logits, T3, 8192, 1000, 1000);

  // coact0 = Act0^T @ Act1 -> [1024, 2048]; split-K 8 (Kc=1024), 1024 blocks
  gemm_nt<MODE_ATOMIC><<<dim3(16, 8, 8), blk, 0, stream>>>(T0, T1, nullptr, coact0,
                                                           1024, 2048, 1024, 2048, 2048);
  // coact1 = Act1^T @ Act2 -> [2048, 2048]; split-K 4 (Kc=2048), 1024 blocks
  gemm_nt<MODE_ATOMIC><<<dim3(16, 16, 4), blk, 0, stream>>>(T1, T2, nullptr, coact1,
                                                            2048, 2048, 2048, 2048, 2048);
  // coact2 = Act2^T @ Act3 -> [2048, 1000]; split-K 8 (Kc=1024), 1024 blocks
  gemm_nt<MODE_ATOMIC><<<dim3(8, 16, 8), blk, 0, stream>>>(T2, T3, nullptr, coact2,
                                                           2048, 1024, 1024, 1000, 1000);
}

// Round 3
// 656.312 us; speedup vs baseline: 1.3539x; 1.1457x over previous
//
#include <hip/hip_runtime.h>
#include <hip/hip_bf16.h>

// ---------------------------------------------------------------------------
// HebbianNetwork: logits + 3 coactivation matrices.
//   B=8192, D_IN=1024, H1=H2=2048, N_CLS=1000
// Forward: bf16 MFMA (16x16x32) 128x128-tile NT gemm.
// R1: coact GEMMs were 1 block/CU -> split-K with fp32 atomicAdd (exact).
// R2: coacts are 0/1 matmuls -> int8 MFMA (16x16x64), BK=64, half the
//     staging bytes + half the iterations + 2x MFMA rate. Exact in i32.
// ---------------------------------------------------------------------------

#define BM 128
#define BN 128
#define BK 32

typedef short v8s __attribute__((ext_vector_type(8)));
typedef float v4f __attribute__((ext_vector_type(4)));
typedef int v4i __attribute__((ext_vector_type(4)));

enum { MODE_RELU = 0, MODE_LOGITS = 1 };

__device__ __forceinline__ void async_cp16(const void* gsrc, void* ldst) {
  __builtin_amdgcn_global_load_lds(
      (const __attribute__((address_space(1))) void*)gsrc,
      (__attribute__((address_space(3))) void*)ldst, 16, 0, 0);
}

// ---------------- bf16 forward gemm --------------------------------------
// C[M,N] = A[M,K] @ B[N,K]^T + bias, A,B bf16 row-major inner-K.
// MODE_RELU:   store bf16 relu(acc+bias) to Cout [M, ldc]
// MODE_LOGITS: store fp32 (acc+bias) to Cout [M, ldc] for col < n_store
template <int MODE>
__global__ __launch_bounds__(256) void gemm_nt(
    const __hip_bfloat16* __restrict__ A, const __hip_bfloat16* __restrict__ B,
    const float* __restrict__ bias, void* __restrict__ Cout,
    int M, int N, int K, int n_store, int ldc) {
  __shared__ __hip_bfloat16 sA[BM * BK];
  __shared__ __hip_bfloat16 sB[BN * BK];
  const int t = threadIdx.x;
  const int m0 = blockIdx.y * BM;
  const int n0 = blockIdx.x * BN;

  const int srow = t >> 2;           // 0..63
  const int scol = (t & 3) * 8;      // 0,8,16,24
  const __hip_bfloat16* ag0 = A + (size_t)(m0 + srow) * K + scol;
  const __hip_bfloat16* ag1 = A + (size_t)(m0 + srow + 64) * K + scol;
  const __hip_bfloat16* bg0 = B + (size_t)(n0 + srow) * K + scol;
  const __hip_bfloat16* bg1 = B + (size_t)(n0 + srow + 64) * K + scol;
  char* lA0 = (char*)sA + t * 16;
  char* lA1 = (char*)sA + 4096 + t * 16;
  char* lB0 = (char*)sB + t * 16;
  char* lB1 = (char*)sB + 4096 + t * 16;

  const int lane = t & 63;
  const int wave = t >> 6;
  const int wm = (wave & 1) * 64;
  const int wn = (wave >> 1) * 64;
  const int lrow = lane & 15;
  const int quad = lane >> 4;

  const __hip_bfloat16* pa = sA + (wm + lrow) * BK + quad * 8;
  const __hip_bfloat16* pb = sB + (wn + lrow) * BK + quad * 8;

  v4f acc[4][4] = {};

  for (int k0 = 0; k0 < K; k0 += BK) {
    async_cp16(ag0 + k0, lA0);
    async_cp16(ag1 + k0, lA1);
    async_cp16(bg0 + k0, lB0);
    async_cp16(bg1 + k0, lB1);
    __syncthreads();

    v8s af[4], bf[4];
#pragma unroll
    for (int i = 0; i < 4; i++) {
      af[i] = *(const v8s*)(pa + i * 16 * BK);
      bf[i] = *(const v8s*)(pb + i * 16 * BK);
    }
#pragma unroll
    for (int mi = 0; mi < 4; mi++)
#pragma unroll
      for (int ni = 0; ni < 4; ni++)
        acc[mi][ni] = __builtin_amdgcn_mfma_f32_16x16x32_bf16(
            af[mi], bf[ni], acc[mi][ni], 0, 0, 0);
    __syncthreads();
  }

  // epilogue: C/D layout col=lane&15, row=quad*4+reg
#pragma unroll
  for (int ni = 0; ni < 4; ni++) {
    const int col = n0 + wn + ni * 16 + lrow;
    float bv = 0.f;
    if (MODE == MODE_RELU) bv = bias[col];
    if (MODE == MODE_LOGITS && col < n_store) bv = bias[col];
#pragma unroll
    for (int mi = 0; mi < 4; mi++) {
      const int rowb = m0 + wm + mi * 16 + quad * 4;
#pragma unroll
      for (int r = 0; r < 4; r++) {
        const int row = rowb + r;
        const float v = acc[mi][ni][r] + bv;
        if (MODE == MODE_RELU) {
          ((__hip_bfloat16*)Cout)[(size_t)row * ldc + col] =
              __float2bfloat16(v > 0.f ? v : 0.f);
        } else {
          if (col < n_store)
            ((float*)Cout)[(size_t)row * ldc + col] = v;
        }
      }
    }
  }
}

// ---------------- int8 coact gemm ----------------------------------------
// C[M,N] += A[M,K] @ B[N,K]^T, A,B int8 (0/1) row-major inner-K.
// Split-K over blockIdx.z (chunk Kc); fp32 atomicAdd epilogue (exact: i32
// partials < 2^24). BK=64, LDS 2x8KB, 16x16x64 i8 MFMA.
__global__ __launch_bounds__(256) void gemm_nt_i8(
    const char* __restrict__ A, const char* __restrict__ B,
    float* __restrict__ Cout, int M, int N, int Kc, int n_store, int ldc) {
  __shared__ char sA[BM * 64];
  __shared__ char sB[BN * 64];
  const int t = threadIdx.x;
  const int m0 = blockIdx.y * BM;
  const int n0 = blockIdx.x * BN;
  const int kbeg = blockIdx.z * Kc;
  const int kend = kbeg + Kc;
  const size_t K = (size_t)Kc * gridDim.z;  // full K (row stride, bytes)

  // staging: 128x64 i8 tile = 8KB; thread t stages chunks t and t+256
  // chunk c -> row c>>2, byte col (c&3)*16; lds offset c*16 (lane-contiguous)
  const int srow = t >> 2;           // 0..63
  const int scol = (t & 3) * 16;     // 0,16,32,48
  const char* ag0 = A + (size_t)(m0 + srow) * K + scol;
  const char* ag1 = A + (size_t)(m0 + srow + 64) * K + scol;
  const char* bg0 = B + (size_t)(n0 + srow) * K + scol;
  const char* bg1 = B + (size_t)(n0 + srow + 64) * K + scol;
  char* lA0 = sA + t * 16;
  char* lA1 = sA + 4096 + t * 16;
  char* lB0 = sB + t * 16;
  char* lB1 = sB + 4096 + t * 16;

  const int lane = t & 63;
  const int wave = t >> 6;
  const int wm = (wave & 1) * 64;
  const int wn = (wave >> 1) * 64;
  const int lrow = lane & 15;
  const int quad = lane >> 4;

  // A-fragment: lane holds 16 contiguous k at k = quad*16 (extends verified
  // bf16 pattern k=quad*8 to the 4-VGPR i8 operand)
  const char* pa = sA + (wm + lrow) * 64 + quad * 16;
  const char* pb = sB + (wn + lrow) * 64 + quad * 16;

  v4i acc[4][4] = {};

  for (int k0 = kbeg; k0 < kend; k0 += 64) {
    async_cp16(ag0 + k0, lA0);
    async_cp16(ag1 + k0, lA1);
    async_cp16(bg0 + k0, lB0);
    async_cp16(bg1 + k0, lB1);
    __syncthreads();

    v4i af[4], bf[4];
#pragma unroll
    for (int i = 0; i < 4; i++) {
      af[i] = *(const v4i*)(pa + i * 16 * 64);
      bf[i] = *(const v4i*)(pb + i * 16 * 64);
    }
#pragma unroll
    for (int mi = 0; mi < 4; mi++)
#pragma unroll
      for (int ni = 0; ni < 4; ni++)
        acc[mi][ni] = __builtin_amdgcn_mfma_i32_16x16x64_i8(
            af[mi], bf[ni], acc[mi][ni], 0, 0, 0);
    __syncthreads();
  }

  // epilogue: C/D layout col=lane&15, row=quad*4+reg (dtype-independent)
#pragma unroll
  for (int ni = 0; ni < 4; ni++) {
    const int col = n0 + wn + ni * 16 + lrow;
    if (col >= n_store) continue;
#pragma unroll
    for (int mi = 0; mi < 4; mi++) {
      const int rowb = m0 + wm + mi * 16 + quad * 4;
#pragma unroll
      for (int r = 0; r < 4; r++) {
        atomicAdd(&Cout[(size_t)(rowb + r) * ldc + col],
                  (float)acc[mi][ni][r]);
      }
    }
  }
}

// ---------------------------------------------------------------------------
__device__ __forceinline__ float tofl(float v) { return v; }
__device__ __forceinline__ float tofl(__hip_bfloat16 v) { return __bfloat162float(v); }

// out[c][r] = (in[r][c] > 0) ? 1 : 0 (int8). out is [Cpad=gridDim.x*64, R].
// Columns >= Cphys produce 0.
template <typename Tin>
__global__ __launch_bounds__(256) void transpose_bin8(
    const Tin* __restrict__ in, char* __restrict__ out,
    int R, int ldin, int Cphys) {
  __shared__ char tile[64][65];
  const int c0 = blockIdx.x * 64;
  const int r0 = blockIdx.y * 64;
  const int tx = threadIdx.x & 63;
  const int ty = threadIdx.x >> 6;  // 0..3
#pragma unroll
  for (int i = 0; i < 64; i += 4) {
    const int c = c0 + tx;
    const int r = r0 + ty + i;
    float v = 0.f;
    if (c < Cphys) v = tofl(in[(size_t)r * ldin + c]);
    tile[ty + i][tx] = (v > 0.f) ? 1 : 0;
  }
  __syncthreads();
  // write: thread (u = t&15, cg = t>>4) stores char4 chunks down each column
  const int u = threadIdx.x & 15;
  const int cg = threadIdx.x >> 4;
#pragma unroll
  for (int i = 0; i < 64; i += 16) {
    const int col = cg + i;
    char4 v;
    v.x = tile[4 * u + 0][col];
    v.y = tile[4 * u + 1][col];
    v.z = tile[4 * u + 2][col];
    v.w = tile[4 * u + 3][col];
    *(char4*)&out[(size_t)(c0 + col) * R + r0 + 4 * u] = v;
  }
}

__global__ __launch_bounds__(256) void f32_to_bf16_k(
    const float* __restrict__ in, __hip_bfloat16* __restrict__ out, int n4) {
  const int i = blockIdx.x * blockDim.x + threadIdx.x;
  if (i < n4) {
    const float4 v = ((const float4*)in)[i];
    union { __hip_bfloat16 h[4]; ushort4 u; } cv;
    cv.h[0] = __float2bfloat16(v.x);
    cv.h[1] = __float2bfloat16(v.y);
    cv.h[2] = __float2bfloat16(v.z);
    cv.h[3] = __float2bfloat16(v.w);
    ((ushort4*)out)[i] = cv.u;
  }
}

// ---------------------------------------------------------------------------
extern "C" void kernel_launch(void* const* d_in, const int* in_sizes, int n_in,
                              void* d_out, int out_size, void* d_ws, size_t ws_size,
                              hipStream_t stream) {
  const float* x  = (const float*)d_in[0];
  const float* W1 = (const float*)d_in[1];
  const float* b1 = (const float*)d_in[2];
  const float* W2 = (const float*)d_in[3];
  const float* b2 = (const float*)d_in[4];
  const float* W3 = (const float*)d_in[5];
  const float* b3 = (const float*)d_in[6];

  float* logits = (float*)d_out;                        // [8192,1000]
  float* coact0 = logits + (size_t)8192 * 1000;         // [1024,2048]
  float* coact1 = coact0 + (size_t)1024 * 2048;         // [2048,2048]
  float* coact2 = coact1 + (size_t)2048 * 2048;         // [2048,1000]

  char* ws = (char*)d_ws;
  size_t off = 0;
  auto alloc = [&](size_t bytes) {
    char* p = ws + off;
    off += (bytes + 255) & ~(size_t)255;
    return p;
  };
  __hip_bfloat16* X   = (__hip_bfloat16*)alloc((size_t)8192 * 1024 * 2);
  __hip_bfloat16* W1b = (__hip_bfloat16*)alloc((size_t)2048 * 1024 * 2);
  __hip_bfloat16* W2b = (__hip_bfloat16*)alloc((size_t)2048 * 2048 * 2);
  __hip_bfloat16* W3b = (__hip_bfloat16*)alloc((size_t)1024 * 2048 * 2);  // rows 1000..1023 garbage (never stored)
  __hip_bfloat16* A1  = (__hip_bfloat16*)alloc((size_t)8192 * 2048 * 2);
  __hip_bfloat16* A2  = (__hip_bfloat16*)alloc((size_t)8192 * 2048 * 2);
  char* T0 = (char*)alloc((size_t)1024 * 8192);  // Act0^T i8
  char* T1 = (char*)alloc((size_t)2048 * 8192);  // Act1^T i8
  char* T2 = (char*)A1;  // Act2^T aliases A1 (dead after gemm2)
  char* T3 = (char*)A2;  // Act3^T aliases A2 (dead after gemm3)

  const dim3 blk(256);

  // zero the three coact outputs (split-K accumulates atomically into them)
  hipMemsetAsync(coact0, 0,
                 ((size_t)1024 * 2048 + (size_t)2048 * 2048 + (size_t)2048 * 1000) * 4,
                 stream);

  // dtype converts
  f32_to_bf16_k<<<8192 * 1024 / 1024, blk, 0, stream>>>(x,  X,   8192 * 1024 / 4);
  f32_to_bf16_k<<<2048 * 1024 / 1024, blk, 0, stream>>>(W1, W1b, 2048 * 1024 / 4);
  f32_to_bf16_k<<<2048 * 2048 / 1024, blk, 0, stream>>>(W2, W2b, 2048 * 2048 / 4);
  f32_to_bf16_k<<<1000 * 2048 / 1024, blk, 0, stream>>>(W3, W3b, 1000 * 2048 / 4);

  // Act0^T = (x>0)^T  [1024, 8192] i8
  transpose_bin8<float><<<dim3(16, 128), blk, 0, stream>>>(x, T0, 8192, 1024, 1024);

  // z1 = X @ W1^T + b1; A1 = relu(z1) bf16
  gemm_nt<MODE_RELU><<<dim3(16, 64), blk, 0, stream>>>(X, W1b, b1, A1,
                                                       8192, 2048, 1024, 2048, 2048);
  // Act1^T [2048, 8192] i8
  transpose_bin8<__hip_bfloat16><<<dim3(32, 128), blk, 0, stream>>>(A1, T1, 8192, 2048, 2048);

  // z2 = A1 @ W2^T + b2; A2 = relu(z2) bf16
  gemm_nt<MODE_RELU><<<dim3(16, 64), blk, 0, stream>>>(A1, W2b, b2, A2,
                                                       8192, 2048, 2048, 2048, 2048);
  // Act2^T [2048, 8192] i8 (aliases A1 — A1 dead now)
  transpose_bin8<__hip_bfloat16><<<dim3(32, 128), blk, 0, stream>>>(A2, T2, 8192, 2048, 2048);

  // logits = A2 @ W3^T + b3  (N padded to 1024; store cols < 1000)
  gemm_nt<MODE_LOGITS><<<dim3(8, 64), blk, 0, stream>>>(A2, W3b, b3, logits,
                                                        8192, 1024, 2048, 1000, 1000);
  // Act3^T [1024, 8192] i8 from logits (cols >= 1000 -> 0; aliases A2 — dead now)
  transpose_bin8<float><<<dim3(16, 128), blk, 0, stream>>>(logits, T3, 8192, 1000, 1000);

  // coact0 = Act0^T @ Act1 -> [1024, 2048]; split-K 8 (Kc=1024), 1024 blocks
  gemm_nt_i8<<<dim3(16, 8, 8), blk, 0, stream>>>(T0, T1, coact0,
                                                 1024, 2048, 1024, 2048, 2048);
  // coact1 = Act1^T @ Act2 -> [2048, 2048]; split-K 4 (Kc=2048), 1024 blocks
  gemm_nt_i8<<<dim3(16, 16, 4), blk, 0, stream>>>(T1, T2, coact1,
                                                  2048, 2048, 2048, 2048, 2048);
  // coact2 = Act2^T @ Act3 -> [2048, 1000]; split-K 8 (Kc=1024), 1024 blocks
  gemm_nt_i8<<<dim3(8, 16, 8), blk, 0, stream>>>(T2, T3, coact2,
                                                 2048, 1024, 1024, 1000, 1000);
}

// Round 4
// 585.613 us; speedup vs baseline: 1.5174x; 1.1207x over previous
//
#include <hip/hip_runtime.h>
#include <hip/hip_bf16.h>

// ---------------------------------------------------------------------------
// HebbianNetwork: logits + 3 coactivation matrices.
//   B=8192, D_IN=1024, H1=H2=2048, N_CLS=1000
// Forward: bf16 MFMA (16x16x32) 128x128 tile, BK=64, XOR-swizzled LDS.
// Coacts: int8 MFMA (16x16x64) 128x128 tile, BK=128, split-K + atomicAdd.
// R1: split-K coacts (occupancy). R2: i8 coacts (exact 0/1 matmul).
// R3: BK doubled (barrier-drain amortization) + global-side XOR swizzle
//     g = s ^ (row&7) kills the 8.4M/dispatch LDS bank conflicts while
//     keeping global_load_lds's lane-contiguous LDS-dest constraint.
// ---------------------------------------------------------------------------

typedef short v8s __attribute__((ext_vector_type(8)));
typedef float v4f __attribute__((ext_vector_type(4)));
typedef int v4i __attribute__((ext_vector_type(4)));

enum { MODE_RELU = 0, MODE_LOGITS = 1 };

__device__ __forceinline__ void async_cp16(const void* gsrc, void* ldst) {
  __builtin_amdgcn_global_load_lds(
      (const __attribute__((address_space(1))) void*)gsrc,
      (__attribute__((address_space(3))) void*)ldst, 16, 0, 0);
}

// ---------------- bf16 forward gemm (BK=64, swizzled) ---------------------
// C[M,N] = A[M,K] @ B[N,K]^T + bias, A,B bf16 row-major inner-K.
// MODE_RELU:   store bf16 relu(acc+bias) to Cout [M, ldc]
// MODE_LOGITS: store fp32 (acc+bias) to Cout [M, ldc] for col < n_store
template <int MODE>
__global__ __launch_bounds__(256) void gemm_nt(
    const __hip_bfloat16* __restrict__ A, const __hip_bfloat16* __restrict__ B,
    const float* __restrict__ bias, void* __restrict__ Cout,
    int M, int N, int K, int n_store, int ldc) {
  __shared__ __hip_bfloat16 sA[128 * 64];  // 16KB, row stride 64 el (128B)
  __shared__ __hip_bfloat16 sB[128 * 64];
  const int t = threadIdx.x;
  const int m0 = blockIdx.y * 128;
  const int n0 = blockIdx.x * 128;

  // staging: each matrix tile = 128 rows x 8 granules(16B); chunk c = j*256+t
  // LDS byte offset c*16 (lane-contiguous, required by global_load_lds);
  // global granule g = slot ^ (row&7)  [XOR swizzle for conflict-free reads]
  const __hip_bfloat16* aG[4];
  const __hip_bfloat16* bG[4];
  char* lA[4];
  char* lB[4];
#pragma unroll
  for (int j = 0; j < 4; j++) {
    const int c = j * 256 + t;
    const int row = c >> 3;
    const int g = (c & 7) ^ (row & 7);
    aG[j] = A + (size_t)(m0 + row) * K + g * 8;
    bG[j] = B + (size_t)(n0 + row) * K + g * 8;
    lA[j] = (char*)sA + c * 16;
    lB[j] = (char*)sB + c * 16;
  }

  const int lane = t & 63;
  const int wave = t >> 6;
  const int wm = (wave & 1) * 64;
  const int wn = (wave >> 1) * 64;
  const int lrow = lane & 15;
  const int quad = lane >> 4;

  // reader: lane (lrow,quad) wants granule (quad + 4*kg) of row wm+lrow+16i;
  // stored at slot (quad+4*kg) ^ (lrow&7)  (i*16 doesn't affect row&7)
  const int g0 = quad ^ (lrow & 7);
  const __hip_bfloat16* pa0 = sA + (wm + lrow) * 64 + g0 * 8;
  const __hip_bfloat16* pa1 = sA + (wm + lrow) * 64 + (g0 ^ 4) * 8;
  const __hip_bfloat16* pb0 = sB + (wn + lrow) * 64 + g0 * 8;
  const __hip_bfloat16* pb1 = sB + (wn + lrow) * 64 + (g0 ^ 4) * 8;

  v4f acc[4][4] = {};

  for (int k0 = 0; k0 < K; k0 += 64) {
#pragma unroll
    for (int j = 0; j < 4; j++) {
      async_cp16(aG[j] + k0, lA[j]);
      async_cp16(bG[j] + k0, lB[j]);
    }
    __syncthreads();

    v8s a0[4], b0[4], a1[4], b1[4];
#pragma unroll
    for (int i = 0; i < 4; i++) {
      a0[i] = *(const v8s*)(pa0 + i * 16 * 64);
      b0[i] = *(const v8s*)(pb0 + i * 16 * 64);
    }
#pragma unroll
    for (int mi = 0; mi < 4; mi++)
#pragma unroll
      for (int ni = 0; ni < 4; ni++)
        acc[mi][ni] = __builtin_amdgcn_mfma_f32_16x16x32_bf16(
            a0[mi], b0[ni], acc[mi][ni], 0, 0, 0);
#pragma unroll
    for (int i = 0; i < 4; i++) {
      a1[i] = *(const v8s*)(pa1 + i * 16 * 64);
      b1[i] = *(const v8s*)(pb1 + i * 16 * 64);
    }
#pragma unroll
    for (int mi = 0; mi < 4; mi++)
#pragma unroll
      for (int ni = 0; ni < 4; ni++)
        acc[mi][ni] = __builtin_amdgcn_mfma_f32_16x16x32_bf16(
            a1[mi], b1[ni], acc[mi][ni], 0, 0, 0);
    __syncthreads();
  }

  // epilogue: C/D layout col=lane&15, row=quad*4+reg
#pragma unroll
  for (int ni = 0; ni < 4; ni++) {
    const int col = n0 + wn + ni * 16 + lrow;
    float bv = 0.f;
    if (MODE == MODE_RELU) bv = bias[col];
    if (MODE == MODE_LOGITS && col < n_store) bv = bias[col];
#pragma unroll
    for (int mi = 0; mi < 4; mi++) {
      const int rowb = m0 + wm + mi * 16 + quad * 4;
#pragma unroll
      for (int r = 0; r < 4; r++) {
        const int row = rowb + r;
        const float v = acc[mi][ni][r] + bv;
        if (MODE == MODE_RELU) {
          ((__hip_bfloat16*)Cout)[(size_t)row * ldc + col] =
              __float2bfloat16(v > 0.f ? v : 0.f);
        } else {
          if (col < n_store)
            ((float*)Cout)[(size_t)row * ldc + col] = v;
        }
      }
    }
  }
}

// ---------------- int8 coact gemm (BK=128, swizzled) ----------------------
// C[M,N] += A[M,K] @ B[N,K]^T, A,B int8 (0/1) row-major inner-K.
// Split-K over blockIdx.z (chunk Kc); fp32 atomicAdd epilogue (exact: i32
// partials < 2^24).
__global__ __launch_bounds__(256) void gemm_nt_i8(
    const char* __restrict__ A, const char* __restrict__ B,
    float* __restrict__ Cout, int M, int N, int Kc, int n_store, int ldc) {
  __shared__ char sA[128 * 128];  // 16KB, row = 128B = 8 granules(16B)
  __shared__ char sB[128 * 128];
  const int t = threadIdx.x;
  const int m0 = blockIdx.y * 128;
  const int n0 = blockIdx.x * 128;
  const int kbeg = blockIdx.z * Kc;
  const int kend = kbeg + Kc;
  const size_t K = (size_t)Kc * gridDim.z;  // full K (row stride, bytes)

  const char* aG[4];
  const char* bG[4];
  char* lA[4];
  char* lB[4];
#pragma unroll
  for (int j = 0; j < 4; j++) {
    const int c = j * 256 + t;
    const int row = c >> 3;
    const int g = (c & 7) ^ (row & 7);
    aG[j] = A + (size_t)(m0 + row) * K + g * 16;
    bG[j] = B + (size_t)(n0 + row) * K + g * 16;
    lA[j] = sA + c * 16;
    lB[j] = sB + c * 16;
  }

  const int lane = t & 63;
  const int wave = t >> 6;
  const int wm = (wave & 1) * 64;
  const int wn = (wave >> 1) * 64;
  const int lrow = lane & 15;
  const int quad = lane >> 4;

  // lane needs bytes [quad*16,+16) = granule quad (kg adds granule 4)
  const int g0 = quad ^ (lrow & 7);
  const char* pa0 = sA + (wm + lrow) * 128 + g0 * 16;
  const char* pa1 = sA + (wm + lrow) * 128 + (g0 ^ 4) * 16;
  const char* pb0 = sB + (wn + lrow) * 128 + g0 * 16;
  const char* pb1 = sB + (wn + lrow) * 128 + (g0 ^ 4) * 16;

  v4i acc[4][4] = {};

  for (int k0 = kbeg; k0 < kend; k0 += 128) {
#pragma unroll
    for (int j = 0; j < 4; j++) {
      async_cp16(aG[j] + k0, lA[j]);
      async_cp16(bG[j] + k0, lB[j]);
    }
    __syncthreads();

    v4i a0[4], b0[4], a1[4], b1[4];
#pragma unroll
    for (int i = 0; i < 4; i++) {
      a0[i] = *(const v4i*)(pa0 + i * 16 * 128);
      b0[i] = *(const v4i*)(pb0 + i * 16 * 128);
    }
#pragma unroll
    for (int mi = 0; mi < 4; mi++)
#pragma unroll
      for (int ni = 0; ni < 4; ni++)
        acc[mi][ni] = __builtin_amdgcn_mfma_i32_16x16x64_i8(
            a0[mi], b0[ni], acc[mi][ni], 0, 0, 0);
#pragma unroll
    for (int i = 0; i < 4; i++) {
      a1[i] = *(const v4i*)(pa1 + i * 16 * 128);
      b1[i] = *(const v4i*)(pb1 + i * 16 * 128);
    }
#pragma unroll
    for (int mi = 0; mi < 4; mi++)
#pragma unroll
      for (int ni = 0; ni < 4; ni++)
        acc[mi][ni] = __builtin_amdgcn_mfma_i32_16x16x64_i8(
            a1[mi], b1[ni], acc[mi][ni], 0, 0, 0);
    __syncthreads();
  }

  // epilogue: C/D layout col=lane&15, row=quad*4+reg (dtype-independent)
#pragma unroll
  for (int ni = 0; ni < 4; ni++) {
    const int col = n0 + wn + ni * 16 + lrow;
    if (col >= n_store) continue;
#pragma unroll
    for (int mi = 0; mi < 4; mi++) {
      const int rowb = m0 + wm + mi * 16 + quad * 4;
#pragma unroll
      for (int r = 0; r < 4; r++) {
        atomicAdd(&Cout[(size_t)(rowb + r) * ldc + col],
                  (float)acc[mi][ni][r]);
      }
    }
  }
}

// ---------------------------------------------------------------------------
__device__ __forceinline__ float tofl(float v) { return v; }
__device__ __forceinline__ float tofl(__hip_bfloat16 v) { return __bfloat162float(v); }

// out[c][r] = (in[r][c] > 0) ? 1 : 0 (int8). out is [Cpad=gridDim.x*64, R].
// Columns >= Cphys produce 0.
template <typename Tin>
__global__ __launch_bounds__(256) void transpose_bin8(
    const Tin* __restrict__ in, char* __restrict__ out,
    int R, int ldin, int Cphys) {
  __shared__ char tile[64][65];
  const int c0 = blockIdx.x * 64;
  const int r0 = blockIdx.y * 64;
  const int tx = threadIdx.x & 63;
  const int ty = threadIdx.x >> 6;  // 0..3
#pragma unroll
  for (int i = 0; i < 64; i += 4) {
    const int c = c0 + tx;
    const int r = r0 + ty + i;
    float v = 0.f;
    if (c < Cphys) v = tofl(in[(size_t)r * ldin + c]);
    tile[ty + i][tx] = (v > 0.f) ? 1 : 0;
  }
  __syncthreads();
  const int u = threadIdx.x & 15;
  const int cg = threadIdx.x >> 4;
#pragma unroll
  for (int i = 0; i < 64; i += 16) {
    const int col = cg + i;
    char4 v;
    v.x = tile[4 * u + 0][col];
    v.y = tile[4 * u + 1][col];
    v.z = tile[4 * u + 2][col];
    v.w = tile[4 * u + 3][col];
    *(char4*)&out[(size_t)(c0 + col) * R + r0 + 4 * u] = v;
  }
}

// fused f32->bf16 for up to 4 arrays (fewer launches / tails)
struct Cvt4 {
  const float* src[4];
  __hip_bfloat16* dst[4];
  int n4[4];  // float4 counts
};
__global__ __launch_bounds__(256) void f32_to_bf16_multi(Cvt4 c) {
  int i = blockIdx.x * 256 + threadIdx.x;
#pragma unroll
  for (int s = 0; s < 4; s++) {
    if (i < c.n4[s]) {
      const float4 v = ((const float4*)c.src[s])[i];
      union { __hip_bfloat16 h[4]; ushort4 u; } cv;
      cv.h[0] = __float2bfloat16(v.x);
      cv.h[1] = __float2bfloat16(v.y);
      cv.h[2] = __float2bfloat16(v.z);
      cv.h[3] = __float2bfloat16(v.w);
      ((ushort4*)c.dst[s])[i] = cv.u;
      return;
    }
    i -= c.n4[s];
  }
}

// ---------------------------------------------------------------------------
extern "C" void kernel_launch(void* const* d_in, const int* in_sizes, int n_in,
                              void* d_out, int out_size, void* d_ws, size_t ws_size,
                              hipStream_t stream) {
  const float* x  = (const float*)d_in[0];
  const float* W1 = (const float*)d_in[1];
  const float* b1 = (const float*)d_in[2];
  const float* W2 = (const float*)d_in[3];
  const float* b2 = (const float*)d_in[4];
  const float* W3 = (const float*)d_in[5];
  const float* b3 = (const float*)d_in[6];

  float* logits = (float*)d_out;                        // [8192,1000]
  float* coact0 = logits + (size_t)8192 * 1000;         // [1024,2048]
  float* coact1 = coact0 + (size_t)1024 * 2048;         // [2048,2048]
  float* coact2 = coact1 + (size_t)2048 * 2048;         // [2048,1000]

  char* ws = (char*)d_ws;
  size_t off = 0;
  auto alloc = [&](size_t bytes) {
    char* p = ws + off;
    off += (bytes + 255) & ~(size_t)255;
    return p;
  };
  __hip_bfloat16* X   = (__hip_bfloat16*)alloc((size_t)8192 * 1024 * 2);
  __hip_bfloat16* W1b = (__hip_bfloat16*)alloc((size_t)2048 * 1024 * 2);
  __hip_bfloat16* W2b = (__hip_bfloat16*)alloc((size_t)2048 * 2048 * 2);
  __hip_bfloat16* W3b = (__hip_bfloat16*)alloc((size_t)1024 * 2048 * 2);  // rows 1000..1023 garbage (never stored)
  __hip_bfloat16* A1  = (__hip_bfloat16*)alloc((size_t)8192 * 2048 * 2);
  __hip_bfloat16* A2  = (__hip_bfloat16*)alloc((size_t)8192 * 2048 * 2);
  char* T0 = (char*)alloc((size_t)1024 * 8192);  // Act0^T i8
  char* T1 = (char*)alloc((size_t)2048 * 8192);  // Act1^T i8
  char* T2 = (char*)A1;  // Act2^T aliases A1 (dead after gemm2)
  char* T3 = (char*)A2;  // Act3^T aliases A2 (dead after gemm3)

  const dim3 blk(256);

  // zero the three coact outputs (split-K accumulates atomically into them)
  hipMemsetAsync(coact0, 0,
                 ((size_t)1024 * 2048 + (size_t)2048 * 2048 + (size_t)2048 * 1000) * 4,
                 stream);

  // dtype converts (fused)
  {
    Cvt4 c;
    c.src[0] = x;  c.dst[0] = X;   c.n4[0] = 8192 * 1024 / 4;
    c.src[1] = W1; c.dst[1] = W1b; c.n4[1] = 2048 * 1024 / 4;
    c.src[2] = W2; c.dst[2] = W2b; c.n4[2] = 2048 * 2048 / 4;
    c.src[3] = W3; c.dst[3] = W3b; c.n4[3] = 1000 * 2048 / 4;
    const int total = c.n4[0] + c.n4[1] + c.n4[2] + c.n4[3];
    f32_to_bf16_multi<<<(total + 255) / 256, blk, 0, stream>>>(c);
  }

  // Act0^T = (x>0)^T  [1024, 8192] i8
  transpose_bin8<float><<<dim3(16, 128), blk, 0, stream>>>(x, T0, 8192, 1024, 1024);

  // z1 = X @ W1^T + b1; A1 = relu(z1) bf16
  gemm_nt<MODE_RELU><<<dim3(16, 64), blk, 0, stream>>>(X, W1b, b1, A1,
                                                       8192, 2048, 1024, 2048, 2048);
  // Act1^T [2048, 8192] i8
  transpose_bin8<__hip_bfloat16><<<dim3(32, 128), blk, 0, stream>>>(A1, T1, 8192, 2048, 2048);

  // z2 = A1 @ W2^T + b2; A2 = relu(z2) bf16
  gemm_nt<MODE_RELU><<<dim3(16, 64), blk, 0, stream>>>(A1, W2b, b2, A2,
                                                       8192, 2048, 2048, 2048, 2048);
  // Act2^T [2048, 8192] i8 (aliases A1 — A1 dead now)
  transpose_bin8<__hip_bfloat16><<<dim3(32, 128), blk, 0, stream>>>(A2, T2, 8192, 2048, 2048);

  // logits = A2 @ W3^T + b3  (N padded to 1024; store cols < 1000)
  gemm_nt<MODE_LOGITS><<<dim3(8, 64), blk, 0, stream>>>(A2, W3b, b3, logits,
                                                        8192, 1024, 2048, 1000, 1000);
  // Act3^T [1024, 8192] i8 from logits (cols >= 1000 -> 0; aliases A2 — dead now)
  transpose_bin8<float><<<dim3(16, 128), blk, 0, stream>>>(logits, T3, 8192, 1000, 1000);

  // coact0 = Act0^T @ Act1 -> [1024, 2048]; split-K 8 (Kc=1024), 1024 blocks
  gemm_nt_i8<<<dim3(16, 8, 8), blk, 0, stream>>>(T0, T1, coact0,
                                                 1024, 2048, 1024, 2048, 2048);
  // coact1 = Act1^T @ Act2 -> [2048, 2048]; split-K 4 (Kc=2048), 1024 blocks
  gemm_nt_i8<<<dim3(16, 16, 4), blk, 0, stream>>>(T1, T2, coact1,
                                                  2048, 2048, 2048, 2048, 2048);
  // coact2 = Act2^T @ Act3 -> [2048, 1000]; split-K 8 (Kc=1024), 1024 blocks
  gemm_nt_i8<<<dim3(8, 16, 8), blk, 0, stream>>>(T2, T3, coact2,
                                                 2048, 1024, 1024, 1000, 1000);
}

// Round 5
// 466.437 us; speedup vs baseline: 1.9051x; 1.2555x over previous
//
#include <hip/hip_runtime.h>
#include <hip/hip_bf16.h>

// ---------------------------------------------------------------------------
// HebbianNetwork: logits + 3 coactivation matrices.
//   B=8192, D_IN=1024, H1=H2=2048, N_CLS=1000
// Forward: bf16 MFMA (16x16x32) 128x128 tile, BK=64, XOR-swizzled LDS.
// Coacts: int8 MFMA (16x16x64) 128x128 tile, BK=128, split-K.
// R1: split-K coacts (occupancy). R2: i8 coacts (exact 0/1 matmul).
// R3: BK doubled + global-side XOR swizzle g = s ^ (row&7) -> 0 bank conflicts.
// R4: split-K epilogue atomicAdd (50M RMWs) -> plain-store fp32 partials into
//     a 32MiB ws region (aliases dead X/W1-3b buffers) + float4 reduce kernel.
//     Partials are integer-valued < 2^24 -> exact.
// ---------------------------------------------------------------------------

typedef short v8s __attribute__((ext_vector_type(8)));
typedef float v4f __attribute__((ext_vector_type(4)));
typedef int v4i __attribute__((ext_vector_type(4)));

enum { MODE_RELU = 0, MODE_LOGITS = 1 };

__device__ __forceinline__ void async_cp16(const void* gsrc, void* ldst) {
  __builtin_amdgcn_global_load_lds(
      (const __attribute__((address_space(1))) void*)gsrc,
      (__attribute__((address_space(3))) void*)ldst, 16, 0, 0);
}

// ---------------- bf16 forward gemm (BK=64, swizzled) ---------------------
// C[M,N] = A[M,K] @ B[N,K]^T + bias, A,B bf16 row-major inner-K.
// MODE_RELU:   store bf16 relu(acc+bias) to Cout [M, ldc]
// MODE_LOGITS: store fp32 (acc+bias) to Cout [M, ldc] for col < n_store
template <int MODE>
__global__ __launch_bounds__(256) void gemm_nt(
    const __hip_bfloat16* __restrict__ A, const __hip_bfloat16* __restrict__ B,
    const float* __restrict__ bias, void* __restrict__ Cout,
    int M, int N, int K, int n_store, int ldc) {
  __shared__ __hip_bfloat16 sA[128 * 64];  // 16KB, row stride 64 el (128B)
  __shared__ __hip_bfloat16 sB[128 * 64];
  const int t = threadIdx.x;
  const int m0 = blockIdx.y * 128;
  const int n0 = blockIdx.x * 128;

  // staging: tile = 128 rows x 8 granules(16B); chunk c = j*256+t
  // LDS byte offset c*16 (lane-contiguous, required by global_load_lds);
  // global granule g = slot ^ (row&7)  [XOR swizzle -> conflict-free reads]
  const __hip_bfloat16* aG[4];
  const __hip_bfloat16* bG[4];
  char* lA[4];
  char* lB[4];
#pragma unroll
  for (int j = 0; j < 4; j++) {
    const int c = j * 256 + t;
    const int row = c >> 3;
    const int g = (c & 7) ^ (row & 7);
    aG[j] = A + (size_t)(m0 + row) * K + g * 8;
    bG[j] = B + (size_t)(n0 + row) * K + g * 8;
    lA[j] = (char*)sA + c * 16;
    lB[j] = (char*)sB + c * 16;
  }

  const int lane = t & 63;
  const int wave = t >> 6;
  const int wm = (wave & 1) * 64;
  const int wn = (wave >> 1) * 64;
  const int lrow = lane & 15;
  const int quad = lane >> 4;

  // reader: lane (lrow,quad) wants granule (quad + 4*kg) of row wm+lrow+16i;
  // stored at slot (quad+4*kg) ^ (lrow&7)
  const int g0 = quad ^ (lrow & 7);
  const __hip_bfloat16* pa0 = sA + (wm + lrow) * 64 + g0 * 8;
  const __hip_bfloat16* pa1 = sA + (wm + lrow) * 64 + (g0 ^ 4) * 8;
  const __hip_bfloat16* pb0 = sB + (wn + lrow) * 64 + g0 * 8;
  const __hip_bfloat16* pb1 = sB + (wn + lrow) * 64 + (g0 ^ 4) * 8;

  v4f acc[4][4] = {};

  for (int k0 = 0; k0 < K; k0 += 64) {
#pragma unroll
    for (int j = 0; j < 4; j++) {
      async_cp16(aG[j] + k0, lA[j]);
      async_cp16(bG[j] + k0, lB[j]);
    }
    __syncthreads();

    v8s a0[4], b0[4], a1[4], b1[4];
#pragma unroll
    for (int i = 0; i < 4; i++) {
      a0[i] = *(const v8s*)(pa0 + i * 16 * 64);
      b0[i] = *(const v8s*)(pb0 + i * 16 * 64);
    }
#pragma unroll
    for (int mi = 0; mi < 4; mi++)
#pragma unroll
      for (int ni = 0; ni < 4; ni++)
        acc[mi][ni] = __builtin_amdgcn_mfma_f32_16x16x32_bf16(
            a0[mi], b0[ni], acc[mi][ni], 0, 0, 0);
#pragma unroll
    for (int i = 0; i < 4; i++) {
      a1[i] = *(const v8s*)(pa1 + i * 16 * 64);
      b1[i] = *(const v8s*)(pb1 + i * 16 * 64);
    }
#pragma unroll
    for (int mi = 0; mi < 4; mi++)
#pragma unroll
      for (int ni = 0; ni < 4; ni++)
        acc[mi][ni] = __builtin_amdgcn_mfma_f32_16x16x32_bf16(
            a1[mi], b1[ni], acc[mi][ni], 0, 0, 0);
    __syncthreads();
  }

  // epilogue: C/D layout col=lane&15, row=quad*4+reg
#pragma unroll
  for (int ni = 0; ni < 4; ni++) {
    const int col = n0 + wn + ni * 16 + lrow;
    float bv = 0.f;
    if (MODE == MODE_RELU) bv = bias[col];
    if (MODE == MODE_LOGITS && col < n_store) bv = bias[col];
#pragma unroll
    for (int mi = 0; mi < 4; mi++) {
      const int rowb = m0 + wm + mi * 16 + quad * 4;
#pragma unroll
      for (int r = 0; r < 4; r++) {
        const int row = rowb + r;
        const float v = acc[mi][ni][r] + bv;
        if (MODE == MODE_RELU) {
          ((__hip_bfloat16*)Cout)[(size_t)row * ldc + col] =
              __float2bfloat16(v > 0.f ? v : 0.f);
        } else {
          if (col < n_store)
            ((float*)Cout)[(size_t)row * ldc + col] = v;
        }
      }
    }
  }
}

// ---------------- int8 coact gemm (BK=128, swizzled, partial-store) -------
// P_z[M, n_store] = A[M, kz..] @ B[N, kz..]^T for slice z = blockIdx.z.
// A,B int8 (0/1) row-major inner-K. Plain fp32 stores (no RMW); exact
// (i32 partials < 2^24).
__global__ __launch_bounds__(256) void gemm_nt_i8(
    const char* __restrict__ A, const char* __restrict__ B,
    float* __restrict__ P, int M, int N, int Kc, int n_store, size_t slice) {
  __shared__ char sA[128 * 128];  // 16KB, row = 128B = 8 granules(16B)
  __shared__ char sB[128 * 128];
  const int t = threadIdx.x;
  const int m0 = blockIdx.y * 128;
  const int n0 = blockIdx.x * 128;
  const int kbeg = blockIdx.z * Kc;
  const int kend = kbeg + Kc;
  const size_t K = (size_t)Kc * gridDim.z;  // full K (row stride, bytes)
  float* __restrict__ Pz = P + (size_t)blockIdx.z * slice;

  const char* aG[4];
  const char* bG[4];
  char* lA[4];
  char* lB[4];
#pragma unroll
  for (int j = 0; j < 4; j++) {
    const int c = j * 256 + t;
    const int row = c >> 3;
    const int g = (c & 7) ^ (row & 7);
    aG[j] = A + (size_t)(m0 + row) * K + g * 16;
    bG[j] = B + (size_t)(n0 + row) * K + g * 16;
    lA[j] = sA + c * 16;
    lB[j] = sB + c * 16;
  }

  const int lane = t & 63;
  const int wave = t >> 6;
  const int wm = (wave & 1) * 64;
  const int wn = (wave >> 1) * 64;
  const int lrow = lane & 15;
  const int quad = lane >> 4;

  const int g0 = quad ^ (lrow & 7);
  const char* pa0 = sA + (wm + lrow) * 128 + g0 * 16;
  const char* pa1 = sA + (wm + lrow) * 128 + (g0 ^ 4) * 16;
  const char* pb0 = sB + (wn + lrow) * 128 + g0 * 16;
  const char* pb1 = sB + (wn + lrow) * 128 + (g0 ^ 4) * 16;

  v4i acc[4][4] = {};

  for (int k0 = kbeg; k0 < kend; k0 += 128) {
#pragma unroll
    for (int j = 0; j < 4; j++) {
      async_cp16(aG[j] + k0, lA[j]);
      async_cp16(bG[j] + k0, lB[j]);
    }
    __syncthreads();

    v4i a0[4], b0[4], a1[4], b1[4];
#pragma unroll
    for (int i = 0; i < 4; i++) {
      a0[i] = *(const v4i*)(pa0 + i * 16 * 128);
      b0[i] = *(const v4i*)(pb0 + i * 16 * 128);
    }
#pragma unroll
    for (int mi = 0; mi < 4; mi++)
#pragma unroll
      for (int ni = 0; ni < 4; ni++)
        acc[mi][ni] = __builtin_amdgcn_mfma_i32_16x16x64_i8(
            a0[mi], b0[ni], acc[mi][ni], 0, 0, 0);
#pragma unroll
    for (int i = 0; i < 4; i++) {
      a1[i] = *(const v4i*)(pa1 + i * 16 * 128);
      b1[i] = *(const v4i*)(pb1 + i * 16 * 128);
    }
#pragma unroll
    for (int mi = 0; mi < 4; mi++)
#pragma unroll
      for (int ni = 0; ni < 4; ni++)
        acc[mi][ni] = __builtin_amdgcn_mfma_i32_16x16x64_i8(
            a1[mi], b1[ni], acc[mi][ni], 0, 0, 0);
    __syncthreads();
  }

  // epilogue: C/D layout col=lane&15, row=quad*4+reg; dense [M, n_store]
#pragma unroll
  for (int ni = 0; ni < 4; ni++) {
    const int col = n0 + wn + ni * 16 + lrow;
    if (col >= n_store) continue;
#pragma unroll
    for (int mi = 0; mi < 4; mi++) {
      const int rowb = m0 + wm + mi * 16 + quad * 4;
#pragma unroll
      for (int r = 0; r < 4; r++) {
        Pz[(size_t)(rowb + r) * n_store + col] = (float)acc[mi][ni][r];
      }
    }
  }
}

// out[i] = sum_z P[z*slice + i], float4-vectorized. slice in floats.
template <int Z>
__global__ __launch_bounds__(256) void reduce_part(
    const float* __restrict__ P, float* __restrict__ out, int n4, size_t slice) {
  const int i = blockIdx.x * 256 + threadIdx.x;
  if (i >= n4) return;
  float4 s = ((const float4*)P)[i];
#pragma unroll
  for (int z = 1; z < Z; z++) {
    const float4 v = ((const float4*)(P + (size_t)z * slice))[i];
    s.x += v.x; s.y += v.y; s.z += v.z; s.w += v.w;
  }
  ((float4*)out)[i] = s;
}

// ---------------------------------------------------------------------------
__device__ __forceinline__ float tofl(float v) { return v; }
__device__ __forceinline__ float tofl(__hip_bfloat16 v) { return __bfloat162float(v); }

// out[c][r] = (in[r][c] > 0) ? 1 : 0 (int8). out is [Cpad=gridDim.x*64, R].
// Columns >= Cphys produce 0.
template <typename Tin>
__global__ __launch_bounds__(256) void transpose_bin8(
    const Tin* __restrict__ in, char* __restrict__ out,
    int R, int ldin, int Cphys) {
  __shared__ char tile[64][65];
  const int c0 = blockIdx.x * 64;
  const int r0 = blockIdx.y * 64;
  const int tx = threadIdx.x & 63;
  const int ty = threadIdx.x >> 6;  // 0..3
#pragma unroll
  for (int i = 0; i < 64; i += 4) {
    const int c = c0 + tx;
    const int r = r0 + ty + i;
    float v = 0.f;
    if (c < Cphys) v = tofl(in[(size_t)r * ldin + c]);
    tile[ty + i][tx] = (v > 0.f) ? 1 : 0;
  }
  __syncthreads();
  const int u = threadIdx.x & 15;
  const int cg = threadIdx.x >> 4;
#pragma unroll
  for (int i = 0; i < 64; i += 16) {
    const int col = cg + i;
    char4 v;
    v.x = tile[4 * u + 0][col];
    v.y = tile[4 * u + 1][col];
    v.z = tile[4 * u + 2][col];
    v.w = tile[4 * u + 3][col];
    *(char4*)&out[(size_t)(c0 + col) * R + r0 + 4 * u] = v;
  }
}

// fused f32->bf16 for up to 4 arrays (fewer launches / tails)
struct Cvt4 {
  const float* src[4];
  __hip_bfloat16* dst[4];
  int n4[4];  // float4 counts
};
__global__ __launch_bounds__(256) void f32_to_bf16_multi(Cvt4 c) {
  int i = blockIdx.x * 256 + threadIdx.x;
#pragma unroll
  for (int s = 0; s < 4; s++) {
    if (i < c.n4[s]) {
      const float4 v = ((const float4*)c.src[s])[i];
      union { __hip_bfloat16 h[4]; ushort4 u; } cv;
      cv.h[0] = __float2bfloat16(v.x);
      cv.h[1] = __float2bfloat16(v.y);
      cv.h[2] = __float2bfloat16(v.z);
      cv.h[3] = __float2bfloat16(v.w);
      ((ushort4*)c.dst[s])[i] = cv.u;
      return;
    }
    i -= c.n4[s];
  }
}

// ---------------------------------------------------------------------------
extern "C" void kernel_launch(void* const* d_in, const int* in_sizes, int n_in,
                              void* d_out, int out_size, void* d_ws, size_t ws_size,
                              hipStream_t stream) {
  const float* x  = (const float*)d_in[0];
  const float* W1 = (const float*)d_in[1];
  const float* b1 = (const float*)d_in[2];
  const float* W2 = (const float*)d_in[3];
  const float* b2 = (const float*)d_in[4];
  const float* W3 = (const float*)d_in[5];
  const float* b3 = (const float*)d_in[6];

  float* logits = (float*)d_out;                        // [8192,1000]
  float* coact0 = logits + (size_t)8192 * 1000;         // [1024,2048]
  float* coact1 = coact0 + (size_t)1024 * 2048;         // [2048,2048]
  float* coact2 = coact1 + (size_t)2048 * 2048;         // [2048,1000]

  char* ws = (char*)d_ws;
  size_t off = 0;
  auto alloc = [&](size_t bytes) {
    char* p = ws + off;
    off += (bytes + 255) & ~(size_t)255;
    return p;
  };
  __hip_bfloat16* X   = (__hip_bfloat16*)alloc((size_t)8192 * 1024 * 2);  // 16MiB
  __hip_bfloat16* W1b = (__hip_bfloat16*)alloc((size_t)2048 * 1024 * 2);  //  4MiB
  __hip_bfloat16* W2b = (__hip_bfloat16*)alloc((size_t)2048 * 2048 * 2);  //  8MiB
  __hip_bfloat16* W3b = (__hip_bfloat16*)alloc((size_t)1024 * 2048 * 2);  //  4MiB (rows 1000..1023 garbage)
  __hip_bfloat16* A1  = (__hip_bfloat16*)alloc((size_t)8192 * 2048 * 2);
  __hip_bfloat16* A2  = (__hip_bfloat16*)alloc((size_t)8192 * 2048 * 2);
  char* T0 = (char*)alloc((size_t)1024 * 8192);  // Act0^T i8
  char* T1 = (char*)alloc((size_t)2048 * 8192);  // Act1^T i8
  char* T2 = (char*)A1;  // Act2^T aliases A1 (dead after gemm2)
  char* T3 = (char*)A2;  // Act3^T aliases A2 (dead after gemm3)
  // Partial buffer: aliases X..W3b (exactly 32MiB contiguous, dead after
  // gemm3 / all coact inputs are T0..T3). Max use: 4x8MiB or 2x16MiB.
  float* P = (float*)X;

  const dim3 blk(256);

  // dtype converts (fused)
  {
    Cvt4 c;
    c.src[0] = x;  c.dst[0] = X;   c.n4[0] = 8192 * 1024 / 4;
    c.src[1] = W1; c.dst[1] = W1b; c.n4[1] = 2048 * 1024 / 4;
    c.src[2] = W2; c.dst[2] = W2b; c.n4[2] = 2048 * 2048 / 4;
    c.src[3] = W3; c.dst[3] = W3b; c.n4[3] = 1000 * 2048 / 4;
    const int total = c.n4[0] + c.n4[1] + c.n4[2] + c.n4[3];
    f32_to_bf16_multi<<<(total + 255) / 256, blk, 0, stream>>>(c);
  }

  // Act0^T = (x>0)^T  [1024, 8192] i8
  transpose_bin8<float><<<dim3(16, 128), blk, 0, stream>>>(x, T0, 8192, 1024, 1024);

  // z1 = X @ W1^T + b1; A1 = relu(z1) bf16
  gemm_nt<MODE_RELU><<<dim3(16, 64), blk, 0, stream>>>(X, W1b, b1, A1,
                                                       8192, 2048, 1024, 2048, 2048);
  // Act1^T [2048, 8192] i8
  transpose_bin8<__hip_bfloat16><<<dim3(32, 128), blk, 0, stream>>>(A1, T1, 8192, 2048, 2048);

  // z2 = A1 @ W2^T + b2; A2 = relu(z2) bf16
  gemm_nt<MODE_RELU><<<dim3(16, 64), blk, 0, stream>>>(A1, W2b, b2, A2,
                                                       8192, 2048, 2048, 2048, 2048);
  // Act2^T [2048, 8192] i8 (aliases A1 — A1 dead now)
  transpose_bin8<__hip_bfloat16><<<dim3(32, 128), blk, 0, stream>>>(A2, T2, 8192, 2048, 2048);

  // logits = A2 @ W3^T + b3  (N padded to 1024; store cols < 1000)
  gemm_nt<MODE_LOGITS><<<dim3(8, 64), blk, 0, stream>>>(A2, W3b, b3, logits,
                                                        8192, 1024, 2048, 1000, 1000);
  // Act3^T [1024, 8192] i8 from logits (cols >= 1000 -> 0; aliases A2 — dead now)
  transpose_bin8<float><<<dim3(16, 128), blk, 0, stream>>>(logits, T3, 8192, 1000, 1000);

  // coact0 = Act0^T @ Act1 -> [1024, 2048]; z=4 (Kc=2048), partials 4x8MiB
  gemm_nt_i8<<<dim3(16, 8, 4), blk, 0, stream>>>(T0, T1, P,
                                                 1024, 2048, 2048, 2048,
                                                 (size_t)1024 * 2048);
  reduce_part<4><<<1024 * 2048 / 4 / 256, blk, 0, stream>>>(
      P, coact0, 1024 * 2048 / 4, (size_t)1024 * 2048);

  // coact1 = Act1^T @ Act2 -> [2048, 2048]; z=2 (Kc=4096), partials 2x16MiB
  gemm_nt_i8<<<dim3(16, 16, 2), blk, 0, stream>>>(T1, T2, P,
                                                  2048, 2048, 4096, 2048,
                                                  (size_t)2048 * 2048);
  reduce_part<2><<<2048 * 2048 / 4 / 256, blk, 0, stream>>>(
      P, coact1, 2048 * 2048 / 4, (size_t)2048 * 2048);

  // coact2 = Act2^T @ Act3 -> [2048, 1000]; z=4 (Kc=2048), partials 4x~8MB
  gemm_nt_i8<<<dim3(8, 16, 4), blk, 0, stream>>>(T2, T3, P,
                                                 2048, 1024, 2048, 1000,
                                                 (size_t)2048 * 1000);
  reduce_part<4><<<2048 * 1000 / 4 / 256, blk, 0, stream>>>(
      P, coact2, 2048 * 1000 / 4, (size_t)2048 * 1000);
}